// Round 4
// baseline (368.140 us; speedup 1.0000x reference)
//
#include <hip/hip_runtime.h>

// FragAttention: masked prefix-sum along s.
//   x: (S, B, D) f32, src_mask: (B, S) int (True=pad)
//   out: (B, G, 2D) f32, G = S-1
//   left[b,g,d]  = sum_{s<=g} x[s,b,d]*valid[b,s]
//   right[b,g,d] = total[b,d] - left[b,g,d]
//
// R4: two-pass, phase-free. R0-R3 all plateaued ~150us kernel (~2.7 TB/s of
// a 6.3 TB/s copy ceiling); shared trait was the barrier-phased schedule
// (read-burst / barrier / write-burst in near-lockstep at 2-3 blocks/CU ->
// DRAM read/write turnaround thrash). Split:
//   K1: per-chunk masked partials into 8MB ws. Dense reads, 32 waves/CU.
//   K2: barrier-free streaming: offset/total from ws, then per s:
//       load -> run += -> store left/right. Steady mixed 1:2 R:W stream,
//       32 waves/CU, no LDS. nt stores protect x's L3 residency for K2.
// Fallback to the proven R1 single-kernel if ws_size < 8MB.
#define SS 128
#define BB 512
#define DD 512
#define GG 127
#define NBD4 (BB * DD / 4)  // 65536 f4 per s-plane

typedef float f4 __attribute__((ext_vector_type(4)));

// ---------------- K1: partial[q][bd4] over s in [16q, 16q+16) -------------
__global__ __launch_bounds__(256, 8) void k1_partials(
    const float* __restrict__ x, const int* __restrict__ mask,
    float* __restrict__ ws) {
  const int q = blockIdx.x >> 8;      // chunk 0..7
  const int slab = blockIdx.x & 255;  // 256 slabs x 256 f4 = one plane
  const int bd4 = slab * 256 + threadIdx.x;
  const int b = bd4 >> 7;  // 128 f4 per b

  int mm[16];
  const int4* mq = (const int4*)(mask + b * SS + q * 16);
  *(int4*)&mm[0] = mq[0];
  *(int4*)&mm[4] = mq[1];
  *(int4*)&mm[8] = mq[2];
  *(int4*)&mm[12] = mq[3];

  const f4* xq = (const f4*)x + (size_t)(q * 16) * NBD4 + bd4;
  f4 acc = {0.f, 0.f, 0.f, 0.f};
#pragma unroll
  for (int i = 0; i < 16; ++i) {
    f4 t = xq[(size_t)i * NBD4];
    acc += t * (mm[i] ? 0.0f : 1.0f);
  }
  ((f4*)ws)[(size_t)q * NBD4 + bd4] = acc;
}

// ---------------- K2: barrier-free prefix stream --------------------------
__global__ __launch_bounds__(512, 8) void k2_stream(
    const float* __restrict__ x, const int* __restrict__ mask,
    const float* __restrict__ ws, float* __restrict__ out) {
  const int b = blockIdx.x >> 1;
  const int jg = blockIdx.x & 1;
  const int j = jg * 4 + (threadIdx.x >> 7);  // chunk 0..7 (wave-uniform)
  const int c = threadIdx.x & 127;            // f4 column 0..127
  const int bd4 = b * 128 + c;

  // offset = sum of partials of chunks < j; total = sum of all 8.
  const f4* wq = (const f4*)ws + bd4;
  f4 offset = {0.f, 0.f, 0.f, 0.f};
  f4 total = {0.f, 0.f, 0.f, 0.f};
#pragma unroll
  for (int jj = 0; jj < 8; ++jj) {
    f4 p = wq[(size_t)jj * NBD4];
    total += p;
    if (jj < j) offset += p;
  }

  int mm[16];
  const int4* mq = (const int4*)(mask + b * SS + j * 16);
  *(int4*)&mm[0] = mq[0];
  *(int4*)&mm[4] = mq[1];
  *(int4*)&mm[8] = mq[2];
  *(int4*)&mm[12] = mq[3];

  const f4* xq = (const f4*)x + (size_t)(j * 16) * NBD4 + bd4;
  // out[b, g, :] as f4: g-stride 256, b-stride 127*256; right half at +128.
  f4* outL = (f4*)out + (size_t)b * (GG * 256) + (size_t)(j * 16) * 256 + c;

  f4 run = offset;
#pragma unroll
  for (int i = 0; i < 16; ++i) {
    const int s = j * 16 + i;
    if (s < GG) {  // wave-uniform; only chunk 7's last iter skips (s=127
                   // contributes to nothing: total already has it via ws)
      f4 t = xq[(size_t)i * NBD4];
      run += t * (mm[i] ? 0.0f : 1.0f);
      __builtin_nontemporal_store(run, outL + (size_t)i * 256);
      f4 r = total - run;
      __builtin_nontemporal_store(r, outL + (size_t)i * 256 + 128);
    }
  }
}

// ---------------- fallback: proven R1 single-kernel -----------------------
#define CS 8
#define NC 16
#define NCOL 32

__global__ __launch_bounds__(512, 6) void frag_prefix_kernel(
    const float* __restrict__ x, const int* __restrict__ mask,
    float* __restrict__ out) {
  const int tid = threadIdx.x;
  const int b = blockIdx.x >> 2;
  const int dblk = (blockIdx.x & 3) << 7;
  const int col = tid & (NCOL - 1);
  const int j = tid >> 5;

  __shared__ float valid[SS];
  __shared__ f4 part[NC][NCOL];

  if (tid < SS) valid[tid] = mask[b * SS + tid] ? 0.0f : 1.0f;
  __syncthreads();

  const size_t sstride = (size_t)BB * DD / 4;
  const f4* xq = (const f4*)x + (size_t)(j * CS) * sstride +
                 ((size_t)b * DD + dblk) / 4 + col;

  f4 v[CS];
#pragma unroll
  for (int i = 0; i < CS; ++i) {
    f4 t = __builtin_nontemporal_load(xq + (size_t)i * sstride);
    v[i] = t * valid[j * CS + i];
  }

  f4 psum = v[0];
#pragma unroll
  for (int i = 1; i < CS; ++i) psum += v[i];
  part[j][col] = psum;
  __syncthreads();

  f4 offset = {0.f, 0.f, 0.f, 0.f};
  f4 total = {0.f, 0.f, 0.f, 0.f};
#pragma unroll
  for (int jj = 0; jj < NC; ++jj) {
    f4 p = part[jj][col];
    total += p;
    if (jj < j) offset += p;
  }

  f4* op = (f4*)out + ((size_t)b * GG * 2 * DD + dblk) / 4 + col;
  f4 run = offset;
#pragma unroll
  for (int i = 0; i < CS; ++i) {
    run += v[i];
    const int g = j * CS + i;
    if (g < GG) {
      __builtin_nontemporal_store(run, op + (size_t)g * (2 * DD / 4));
      f4 r = total - run;
      __builtin_nontemporal_store(r, op + (size_t)g * (2 * DD / 4) + DD / 4);
    }
  }
}

extern "C" void kernel_launch(void* const* d_in, const int* in_sizes, int n_in,
                              void* d_out, int out_size, void* d_ws, size_t ws_size,
                              hipStream_t stream) {
  const float* x = (const float*)d_in[0];
  const int* mask = (const int*)d_in[1];
  float* out = (float*)d_out;
  const size_t ws_needed = (size_t)8 * NBD4 * sizeof(f4);  // 8 MB
  if (ws_size >= ws_needed && d_ws != nullptr) {
    k1_partials<<<dim3(2048), dim3(256), 0, stream>>>(x, mask, (float*)d_ws);
    k2_stream<<<dim3(1024), dim3(512), 0, stream>>>(
        x, mask, (const float*)d_ws, out);
  } else {
    frag_prefix_kernel<<<dim3(BB * 4), dim3(512), 0, stream>>>(x, mask, out);
  }
}